// Round 30
// baseline (296.602 us; speedup 1.0000x reference)
//
#include <hip/hip_runtime.h>
#include <math.h>

#define N_TOK   2048      // B*T
#define SEQ     1024
#define DIMM    1024
#define NH      16
#define NKV     4
#define HD      64
#define HID     2048
#define NEXP    8
#define QKVW    1536      // fused q|k|v row width

typedef __attribute__((ext_vector_type(4))) float f32x4;
typedef __attribute__((ext_vector_type(8))) short s16x8;
typedef unsigned short u16;

__device__ __forceinline__ u16 f2bf(float f) {
    union { float f; unsigned u; } v; v.f = f;
    unsigned r = v.u + 0x7fffu + ((v.u >> 16) & 1u);
    return (u16)(r >> 16);
}
__device__ __forceinline__ float bf2f(u16 h) {
    union { unsigned u; float f; } v; v.u = ((unsigned)h) << 16;
    return v.f;
}

__device__ __forceinline__ f32x4 mfma16(s16x8 a, s16x8 b, f32x4 c) {
    return __builtin_amdgcn_mfma_f32_16x16x32_bf16(a, b, c, 0, 0, 0);
}

// LDS tile row stride = 64 bf16 = 128 B; XOR-swizzle 16B slot with row&7 (T2)
__device__ __forceinline__ int lds_byte(int row, int byte_in_row, int swz_key) {
    return row * 128 + (byte_in_row ^ ((swz_key & 7) << 4));
}

// load a 16B MFMA fragment (8 bf16) for logical row `row`, k-slice ks (0/1)
__device__ __forceinline__ s16x8 ldfrag(const char* base, int row, int ks, int lane) {
    int b = lds_byte(row, ks * 64 + ((lane >> 4) * 16), row);
    return *(const s16x8*)(base + b);
}

// async 16B global -> LDS (wave-uniform LDS base + lane*16)
__device__ __forceinline__ void gload16(const void* g, void* l) {
    __builtin_amdgcn_global_load_lds(
        (const __attribute__((address_space(1))) void*)g,
        (__attribute__((address_space(3))) void*)l, 16, 0, 0);
}

// coalesced ILP-4 cvt of chunk [cvt_base, cvt_end) of the 12M-float4 wg|wu|wd space
__device__ __forceinline__ void cvt_chunk(int cb, int ncvt, int cvt_base, int cvt_end,
    const float* __restrict__ wg, const float* __restrict__ wu, const float* __restrict__ wd,
    u16* __restrict__ wgb, u16* __restrict__ wub, u16* __restrict__ wdb, int tid)
{
    const int n4 = 4 << 20;   // 4M float4 per tensor
    int i = cvt_base + cb * 1024 + tid;
    int stride = ncvt * 1024;
    for (; i < cvt_end; i += stride) {
        int seg = i >> 22;                // 1024-block never crosses a 4M segment
        int j = i & (n4 - 1);
        const f32x4* in = (const f32x4*)((seg == 0) ? wg : (seg == 1) ? wu : wd);
        ushort4* out = (ushort4*)((seg == 0) ? wgb : (seg == 1) ? wub : wdb);
        f32x4 v0 = __builtin_nontemporal_load(in + j);
        f32x4 v1 = __builtin_nontemporal_load(in + j + 256);
        f32x4 v2 = __builtin_nontemporal_load(in + j + 512);
        f32x4 v3 = __builtin_nontemporal_load(in + j + 768);
        ushort4 o0, o1, o2, o3;
        o0.x = f2bf(v0[0]); o0.y = f2bf(v0[1]); o0.z = f2bf(v0[2]); o0.w = f2bf(v0[3]);
        o1.x = f2bf(v1[0]); o1.y = f2bf(v1[1]); o1.z = f2bf(v1[2]); o1.w = f2bf(v1[3]);
        o2.x = f2bf(v2[0]); o2.y = f2bf(v2[1]); o2.z = f2bf(v2[2]); o2.w = f2bf(v2[3]);
        o3.x = f2bf(v3[0]); o3.y = f2bf(v3[1]); o3.z = f2bf(v3[2]); o3.w = f2bf(v3[3]);
        out[j]       = o0;
        out[j + 256] = o1;
        out[j + 512] = o2;
        out[j + 768] = o3;
    }
}

// ---------------------------------------------------------------- prep1: qkvo split-cvt + rmsnorm(attn)
__global__ __launch_bounds__(256) void prep1(const float* __restrict__ wq,
    const float* __restrict__ wk, const float* __restrict__ wv, const float* __restrict__ wo,
    u16* __restrict__ hi, u16* __restrict__ lo,
    const float* __restrict__ x, const float* __restrict__ w_na,
    u16* __restrict__ oh, u16* __restrict__ ol)
{
    if (blockIdx.x < 1024) {
        int i = blockIdx.x * 256 + threadIdx.x;
        int stride = 1024 * 256;
        for (; i < 655360; i += stride) {
            const float* in; int j;
            if (i < 262144)      { in = wq; j = i; }
            else if (i < 327680) { in = wk; j = i - 262144; }
            else if (i < 393216) { in = wv; j = i - 327680; }
            else                 { in = wo; j = i - 393216; }
            f32x4 v = __builtin_nontemporal_load((const f32x4*)in + j);
            ushort4 h, l;
            h.x = f2bf(v[0]); h.y = f2bf(v[1]); h.z = f2bf(v[2]); h.w = f2bf(v[3]);
            l.x = f2bf(v[0] - bf2f(h.x)); l.y = f2bf(v[1] - bf2f(h.y));
            l.z = f2bf(v[2] - bf2f(h.z)); l.w = f2bf(v[3] - bf2f(h.w));
            reinterpret_cast<ushort4*>(hi)[i] = h;
            reinterpret_cast<ushort4*>(lo)[i] = l;
        }
    } else {
        int row = blockIdx.x - 1024;
        const float4* xr = reinterpret_cast<const float4*>(x + (size_t)row * DIMM);
        const float4* wr = reinterpret_cast<const float4*>(w_na);
        float4 v = xr[threadIdx.x];
        float ss = v.x*v.x + v.y*v.y + v.z*v.z + v.w*v.w;
#pragma unroll
        for (int off = 32; off; off >>= 1) ss += __shfl_xor(ss, off);
        __shared__ float red[4];
        int wid = threadIdx.x >> 6, lane = threadIdx.x & 63;
        if (lane == 0) red[wid] = ss;
        __syncthreads();
        float tot = red[0] + red[1] + red[2] + red[3];
        float inv = rsqrtf(tot * (1.0f/DIMM) + 1e-6f);
        float4 ww = wr[threadIdx.x];
        float4 o;
        o.x = ww.x * v.x * inv;
        o.y = ww.y * v.y * inv;
        o.z = ww.z * v.z * inv;
        o.w = ww.w * v.w * inv;
        ushort4 h, l;
        h.x = f2bf(o.x); h.y = f2bf(o.y); h.z = f2bf(o.z); h.w = f2bf(o.w);
        l.x = f2bf(o.x - bf2f(h.x)); l.y = f2bf(o.y - bf2f(h.y));
        l.z = f2bf(o.z - bf2f(h.z)); l.w = f2bf(o.w - bf2f(h.w));
        reinterpret_cast<ushort4*>(oh + (size_t)row * DIMM)[threadIdx.x] = h;
        reinterpret_cast<ushort4*>(ol + (size_t)row * DIMM)[threadIdx.x] = l;
    }
}

// ---------------------------------------------------------------- rmsnorm + router logits + top2 (all fused)
__global__ __launch_bounds__(256) void rmsnorm_router(const float* __restrict__ x,
    const float* __restrict__ w, const float* __restrict__ rw, const float* __restrict__ rb,
    u16* __restrict__ outb, int* __restrict__ top_idx, float* __restrict__ top_w)
{
    int row = blockIdx.x;
    int tid = threadIdx.x;
    int wid = tid >> 6, lane = tid & 63;
    const float4* xr = reinterpret_cast<const float4*>(x + (size_t)row * DIMM);
    const float4* wr = reinterpret_cast<const float4*>(w);
    float4 v = xr[tid];
    float ss = v.x*v.x + v.y*v.y + v.z*v.z + v.w*v.w;
#pragma unroll
    for (int off = 32; off; off >>= 1) ss += __shfl_xor(ss, off);
    __shared__ float red[4];
    __shared__ float lred[4][NEXP];
    if (lane == 0) red[wid] = ss;
    __syncthreads();
    float tot = red[0] + red[1] + red[2] + red[3];
    float inv = rsqrtf(tot * (1.0f/DIMM) + 1e-6f);
    float4 ww = wr[tid];
    float4 o;
    o.x = ww.x * v.x * inv;
    o.y = ww.y * v.y * inv;
    o.z = ww.z * v.z * inv;
    o.w = ww.w * v.w * inv;
    ushort4 ob;
    ob.x = f2bf(o.x); ob.y = f2bf(o.y); ob.z = f2bf(o.z); ob.w = f2bf(o.w);
    reinterpret_cast<ushort4*>(outb + (size_t)row * DIMM)[tid] = ob;
    float acc[NEXP];
#pragma unroll
    for (int e = 0; e < NEXP; e++) {
        float4 r4 = reinterpret_cast<const float4*>(rw + (size_t)e * DIMM)[tid];
        acc[e] = o.x * r4.x + o.y * r4.y + o.z * r4.z + o.w * r4.w;
    }
#pragma unroll
    for (int e = 0; e < NEXP; e++) {
        float p = acc[e];
#pragma unroll
        for (int off = 32; off; off >>= 1) p += __shfl_xor(p, off);
        acc[e] = p;
    }
    if (lane == 0)
#pragma unroll
        for (int e = 0; e < NEXP; e++) lred[wid][e] = acc[e];
    __syncthreads();
    if (tid == 0) {
        float lg[NEXP];
#pragma unroll
        for (int e = 0; e < NEXP; e++)
            lg[e] = lred[0][e] + lred[1][e] + lred[2][e] + lred[3][e] + rb[e];
        float m = lg[0];
#pragma unroll
        for (int e = 1; e < NEXP; e++) m = fmaxf(m, lg[e]);
        float pe[NEXP], s = 0.f;
#pragma unroll
        for (int e = 0; e < NEXP; e++) { pe[e] = __expf(lg[e] - m); s += pe[e]; }
        int i1 = 0; float v1 = pe[0];
#pragma unroll
        for (int e = 1; e < NEXP; e++) if (pe[e] > v1) { v1 = pe[e]; i1 = e; }
        int i2 = -1; float v2 = -1.f;
#pragma unroll
        for (int e = 0; e < NEXP; e++) if (e != i1 && pe[e] > v2) { v2 = pe[e]; i2 = e; }
        v1 /= s; v2 /= s;
        float den = v1 + v2 + 1e-9f;
        top_idx[2 * row] = i1; top_idx[2 * row + 1] = i2;
        top_w[2 * row] = v1 / den; top_w[2 * row + 1] = v2 / den;
    }
}

// ---------------------------------------------------------------- single-block routing build
__global__ __launch_bounds__(256) void route_build(const int* __restrict__ top_idx,
    const float* __restrict__ top_w, int* __restrict__ counts, int* __restrict__ offs,
    int* __restrict__ assign_token, float* __restrict__ assign_w)
{
    __shared__ int lcnt[NEXP], loff[NEXP], lpos[NEXP];
    int tid = threadIdx.x;
    if (tid < NEXP) { lcnt[tid] = 0; lpos[tid] = 0; }
    __syncthreads();
    for (int i = tid; i < 2 * N_TOK; i += 256)
        atomicAdd(&lcnt[top_idx[i]], 1);
    __syncthreads();
    if (tid == 0) {
        int s = 0;
        for (int e = 0; e < NEXP; e++) { loff[e] = s; s += lcnt[e]; }
    }
    __syncthreads();
    if (tid < NEXP) { counts[tid] = lcnt[tid]; offs[tid] = loff[tid]; }
    for (int i = tid; i < 2 * N_TOK; i += 256) {
        int e = top_idx[i];
        int p = atomicAdd(&lpos[e], 1);
        int r = loff[e] + p;
        assign_token[r] = i >> 1;
        assign_w[r] = top_w[i];
    }
}

// ---------------------------------------------------------------- split-bf16 GEMM + MoE cvt tail (1-D grid)
__global__ __launch_bounds__(256) void gemm_cvt(const u16* __restrict__ Ah_,
    const u16* __restrict__ Al_, const u16* __restrict__ Bh_, const u16* __restrict__ Bl_,
    float* __restrict__ C, const float* __restrict__ R, int M, int N, int K, int ldc,
    int gx, int gy,
    const float* __restrict__ wg, const float* __restrict__ wu, const float* __restrict__ wd,
    u16* __restrict__ wgb, u16* __restrict__ wub, u16* __restrict__ wdb,
    int cvt_base, int cvt_end, int ncvt)
{
    int blk = blockIdx.x;
    if (blk >= gx * gy) {
        cvt_chunk(blk - gx * gy, ncvt, cvt_base, cvt_end, wg, wu, wd, wgb, wub, wdb, threadIdx.x);
        return;
    }
    __shared__ __align__(16) u16 Ah[128 * 64], Al[128 * 64];
    __shared__ __align__(16) u16 Bh[64 * 64],  Bl[64 * 64];
    int tid = threadIdx.x;
    int m0 = (blk / gx) * 128, n0 = (blk % gx) * 64;
    int lane = tid & 63, wv = tid >> 6;
    int wm = wv >> 1, wn = wv & 1;
    int sr = lane >> 3, sc = lane & 7;

    f32x4 acc[4][2];
#pragma unroll
    for (int i = 0; i < 4; i++)
#pragma unroll
        for (int j = 0; j < 2; j++) acc[i][j] = f32x4{0.f, 0.f, 0.f, 0.f};

    const int NT = K >> 6;
    int ph = (blk * 5) & (NT - 1);

    for (int tt = 0; tt < NT; ++tt) {
        int k0 = ((tt + ph) & (NT - 1)) << 6;
#pragma unroll
        for (int i = 0; i < 4; i++) {
            int row = wv * 32 + i * 8 + sr;
            int c = sc ^ (row & 7);
            size_t g = (size_t)(m0 + row) * K + k0 + c * 8;
            gload16(Ah_ + g, (void*)(Ah + (wv * 4 + i) * 512));
            gload16(Al_ + g, (void*)(Al + (wv * 4 + i) * 512));
        }
#pragma unroll
        for (int i = 0; i < 2; i++) {
            int row = wv * 16 + i * 8 + sr;
            int c = sc ^ (row & 7);
            size_t g = (size_t)(n0 + row) * K + k0 + c * 8;
            gload16(Bh_ + g, (void*)(Bh + (wv * 2 + i) * 512));
            gload16(Bl_ + g, (void*)(Bl + (wv * 2 + i) * 512));
        }
        __syncthreads();
#pragma unroll
        for (int ks = 0; ks < 2; ++ks) {
            s16x8 afh[4], afl[4], bfh[2], bfl[2];
#pragma unroll
            for (int mi = 0; mi < 4; mi++) {
                int row = wm * 64 + mi * 16 + (lane & 15);
                afh[mi] = ldfrag((const char*)Ah, row, ks, lane);
                afl[mi] = ldfrag((const char*)Al, row, ks, lane);
            }
#pragma unroll
            for (int nj = 0; nj < 2; nj++) {
                int row = wn * 32 + nj * 16 + (lane & 15);
                bfh[nj] = ldfrag((const char*)Bh, row, ks, lane);
                bfl[nj] = ldfrag((const char*)Bl, row, ks, lane);
            }
#pragma unroll
            for (int mi = 0; mi < 4; mi++)
#pragma unroll
                for (int nj = 0; nj < 2; nj++) {
                    acc[mi][nj] = mfma16(afl[mi], bfh[nj], acc[mi][nj]);
                    acc[mi][nj] = mfma16(afh[mi], bfl[nj], acc[mi][nj]);
                    acc[mi][nj] = mfma16(afh[mi], bfh[nj], acc[mi][nj]);
                }
        }
        __syncthreads();
    }
#pragma unroll
    for (int mi = 0; mi < 4; mi++)
#pragma unroll
        for (int nj = 0; nj < 2; nj++)
#pragma unroll
            for (int r = 0; r < 4; r++) {
                int m = m0 + wm * 64 + mi * 16 + (lane >> 4) * 4 + r;
                int n = n0 + wn * 32 + nj * 16 + (lane & 15);
                float v = acc[mi][nj][r];
                if (R) v += R[(size_t)m * ldc + n];
                C[(size_t)m * ldc + n] = v;
            }
}

// ---------------------------------------------------------------- prep2: RoPE(q,k) + V transpose (merged)
__global__ __launch_bounds__(256) void prep2(const float* __restrict__ qkvb,
    const float* __restrict__ cs, const float* __restrict__ sn,
    u16* __restrict__ qsh, u16* __restrict__ qsl,
    u16* __restrict__ ksh, u16* __restrict__ ksl,
    u16* __restrict__ vth, u16* __restrict__ vtl)
{
    const int ROPE_BLOCKS = (N_TOK * (NH + NKV) * 32) / 256;   // 5120
    if (blockIdx.x < ROPE_BLOCKS) {
        int gid = blockIdx.x * 256 + threadIdx.x;
        const int QTOT = N_TOK * NH * 32;
        int nheads, base_col, out_w;
        u16 *oh, *ol;
        if (gid < QTOT) {
            nheads = NH; base_col = 0; out_w = NH * HD; oh = qsh; ol = qsl;
        } else {
            gid -= QTOT;
            nheads = NKV; base_col = 1024; out_w = NKV * HD; oh = ksh; ol = ksl;
        }
        int i = gid & 31;
        int h = (gid >> 5) % nheads;
        int n = gid / (32 * nheads);
        int t = n & (SEQ - 1);
        const float* p = qkvb + (size_t)n * QKVW + base_col + h * HD + 2 * i;
        float xe = p[0], xo = p[1];
        float c = cs[t * 32 + i], s = sn[t * 32 + i];
        float re = xe * c - xo * s;
        float ro = xe * s + xo * c;
        size_t o = (size_t)n * out_w + h * HD + 2 * i;
        u16 reh = f2bf(re), roh = f2bf(ro);
        oh[o] = reh;     oh[o + 1] = roh;
        ol[o] = f2bf(re - bf2f(reh));
        ol[o + 1] = f2bf(ro - bf2f(roh));
    } else {
        __shared__ float t[64][65];
        int r = blockIdx.x - ROPE_BLOCKS;       // 128 blocks: 32 x 4
        int bx = r & 31;
        int by = r >> 5;
        int tid = threadIdx.x;
        int c4 = tid & 15, r0 = tid >> 4;
#pragma unroll
        for (int i = 0; i < 4; i++) {
            int row = r0 + i * 16;
            float4 vv = *(const float4*)(qkvb + (size_t)(bx * 64 + row) * QKVW + 1280 + by * 64 + c4 * 4);
            t[c4 * 4 + 0][row] = vv.x;
            t[c4 * 4 + 1][row] = vv.y;
            t[c4 * 4 + 2][row] = vv.z;
            t[c4 * 4 + 3][row] = vv.w;
        }
        __syncthreads();
#pragma unroll
        for (int i = 0; i < 4; i++) {
            int drow = r0 + i * 16;
            ushort4 hh, ll;
            float a = t[drow][c4 * 4 + 0], b = t[drow][c4 * 4 + 1];
            float c = t[drow][c4 * 4 + 2], d = t[drow][c4 * 4 + 3];
            hh.x = f2bf(a); hh.y = f2bf(b); hh.z = f2bf(c); hh.w = f2bf(d);
            ll.x = f2bf(a - bf2f(hh.x)); ll.y = f2bf(b - bf2f(hh.y));
            ll.z = f2bf(c - bf2f(hh.z)); ll.w = f2bf(d - bf2f(hh.w));
            size_t o = ((size_t)(by * 64 + drow) * N_TOK + bx * 64 + c4 * 4) >> 2;
            reinterpret_cast<ushort4*>(vth)[o] = hh;
            reinterpret_cast<ushort4*>(vtl)[o] = ll;
        }
    }
}

// ---------------------------------------------------------------- attention (kt-split for qt>=8) + MoE weight cvt
// blocks [0,512): heavy-tile halves (b,h,qt>=8)x2 -> fp32 partials (pO,pM,pL)
// blocks [512,768): light tiles (qt<8) -> direct split-bf16 output
// blocks [768,1792): cvt chunk
__global__ __launch_bounds__(256) void attn_cvt(const u16* __restrict__ qsh,
    const u16* __restrict__ qsl, const u16* __restrict__ ksh, const u16* __restrict__ ksl,
    const u16* __restrict__ vth, const u16* __restrict__ vtl,
    u16* __restrict__ outh, u16* __restrict__ outl,
    float* __restrict__ pO, float* __restrict__ pM, float* __restrict__ pL,
    const float* __restrict__ wg, const float* __restrict__ wu, const float* __restrict__ wd,
    u16* __restrict__ wgb, u16* __restrict__ wub, u16* __restrict__ wdb,
    int cvt_base, int cvt_end, int ncvt)
{
    if (blockIdx.x >= 768) {
        cvt_chunk(blockIdx.x - 768, ncvt, cvt_base, cvt_end, wg, wu, wd, wgb, wub, wdb, threadIdx.x);
        return;
    }
    int bi = blockIdx.x;
    int b, h, qt, kt_lo, kt_hi;
    bool partial;
    if (bi < 512) {                       // heavy halves
        int part = bi & 1;
        int t = bi >> 1;                  // 0..255
        b = t >> 7; h = (t >> 3) & 15; qt = 15 - (t & 7);   // qt in 8..15
        int half = (qt + 1) >> 1;
        kt_lo = part ? half : 0;
        kt_hi = part ? qt : half - 1;
        partial = true;
    } else {                              // light tiles
        int idx = bi - 512;               // 0..255
        b = idx >> 7; h = (idx >> 3) & 15; qt = 7 - (idx & 7);
        kt_lo = 0; kt_hi = qt;
        partial = false;
    }
    int kvh = h >> 2;
    int tid = threadIdx.x;
    int lane = tid & 63, wv = tid >> 6;
    int q0 = qt * 64;
    int sr = lane >> 3, sc = lane & 7;

    // Q buffers are consumed into registers before the K-loop, then reused as P buffers.
    __shared__ __align__(16) u16 Qh[64 * 64], Ql[64 * 64];   // later: Ph, Pl (per-wave 2KB chunks)
    __shared__ __align__(16) u16 Kh[64 * 64], Kl[64 * 64];
    __shared__ __align__(16) u16 Vh[64 * 64], Vl[64 * 64];

#pragma unroll
    for (int i = 0; i < 2; i++) {
        int row = wv * 16 + i * 8 + sr;
        int c = sc ^ (row & 7);
        size_t g = (size_t)(b * SEQ + q0 + row) * (NH * HD) + h * HD + c * 8;
        gload16(qsh + g, (void*)(Qh + (wv * 2 + i) * 512));
        gload16(qsl + g, (void*)(Ql + (wv * 2 + i) * 512));
    }
    __syncthreads();

    s16x8 aQh[2], aQl[2];
#pragma unroll
    for (int ks = 0; ks < 2; ks++) {
        aQh[ks] = ldfrag((const char*)Qh, wv * 16 + (lane & 15), ks, lane);
        aQl[ks] = ldfrag((const char*)Ql, wv * 16 + (lane & 15), ks, lane);
    }

    float m_run[4], l_run[4];
    f32x4 acc_o[4];
#pragma unroll
    for (int r = 0; r < 4; r++) { m_run[r] = -1e30f; l_run[r] = 0.f; }
#pragma unroll
    for (int nj = 0; nj < 4; nj++) acc_o[nj] = f32x4{0.f, 0.f, 0.f, 0.f};

    for (int kt = kt_lo; kt <= kt_hi; kt++) {
        int kbase = kt * 64;
        __syncthreads();
#pragma unroll
        for (int i = 0; i < 2; i++) {
            int row = wv * 16 + i * 8 + sr;
            int c = sc ^ (row & 7);
            size_t gk = (size_t)(b * SEQ + kbase + row) * (NKV * HD) + kvh * HD + c * 8;
            size_t gv = (size_t)(kvh * HD + row) * N_TOK + b * SEQ + kbase + c * 8;
            gload16(ksh + gk, (void*)(Kh + (wv * 2 + i) * 512));
            gload16(ksl + gk, (void*)(Kl + (wv * 2 + i) * 512));
            gload16(vth + gv, (void*)(Vh + (wv * 2 + i) * 512));
            gload16(vtl + gv, (void*)(Vl + (wv * 2 + i) * 512));
        }
        __syncthreads();

        f32x4 sacc[4];
#pragma unroll
        for (int nj = 0; nj < 4; nj++) sacc[nj] = f32x4{0.f, 0.f, 0.f, 0.f};
#pragma unroll
        for (int ks = 0; ks < 2; ks++) {
#pragma unroll
            for (int nj = 0; nj < 4; nj++) {
                s16x8 bKh = ldfrag((const char*)Kh, nj * 16 + (lane & 15), ks, lane);
                s16x8 bKl = ldfrag((const char*)Kl, nj * 16 + (lane & 15), ks, lane);
                sacc[nj] = mfma16(aQl[ks], bKh, sacc[nj]);
                sacc[nj] = mfma16(aQh[ks], bKl, sacc[nj]);
                sacc[nj] = mfma16(aQh[ks], bKh, sacc[nj]);
            }
        }

        float sv[4][4];
#pragma unroll
        for (int nj = 0; nj < 4; nj++)
#pragma unroll
            for (int r = 0; r < 4; r++) {
                float s = sacc[nj][r] * 0.125f;
                if (kt == qt) {
                    int row_loc = wv * 16 + (lane >> 4) * 4 + r;
                    int col_loc = nj * 16 + (lane & 15);
                    if (col_loc > row_loc) s = -1e30f;
                }
                sv[nj][r] = s;
            }

        float p[4][4];
#pragma unroll
        for (int r = 0; r < 4; r++) {
            float mx = fmaxf(fmaxf(sv[0][r], sv[1][r]), fmaxf(sv[2][r], sv[3][r]));
            mx = fmaxf(mx, __shfl_xor(mx, 1));
            mx = fmaxf(mx, __shfl_xor(mx, 2));
            mx = fmaxf(mx, __shfl_xor(mx, 4));
            mx = fmaxf(mx, __shfl_xor(mx, 8));
            float m_new = fmaxf(m_run[r], mx);
            float corr = __expf(m_run[r] - m_new);
            float ps = 0.f;
#pragma unroll
            for (int nj = 0; nj < 4; nj++) {
                float pv = __expf(sv[nj][r] - m_new);
                p[nj][r] = pv;
                ps += pv;
            }
            ps += __shfl_xor(ps, 1);
            ps += __shfl_xor(ps, 2);
            ps += __shfl_xor(ps, 4);
            ps += __shfl_xor(ps, 8);
            l_run[r] = l_run[r] * corr + ps;
            m_run[r] = m_new;
#pragma unroll
            for (int nj = 0; nj < 4; nj++) acc_o[nj][r] *= corr;
        }

        // P (split) into per-wave 2KB chunks aliased over Qh/Ql
        char* phb = (char*)Qh + wv * 2048;
        char* plb = (char*)Ql + wv * 2048;
#pragma unroll
        for (int nj = 0; nj < 4; nj++)
#pragma unroll
            for (int r = 0; r < 4; r++) {
                int row = (lane >> 4) * 4 + r;
                int col = nj * 16 + (lane & 15);
                u16 hh = f2bf(p[nj][r]);
                u16 ll = f2bf(p[nj][r] - bf2f(hh));
                int byte = lds_byte(row, col * 2, row);
                *(u16*)(phb + byte) = hh;
                *(u16*)(plb + byte) = ll;
            }

#pragma unroll
        for (int ks = 0; ks < 2; ks++) {
            s16x8 aPh = ldfrag(phb, lane & 15, ks, lane);
            s16x8 aPl = ldfrag(plb, lane & 15, ks, lane);
#pragma unroll
            for (int nj = 0; nj < 4; nj++) {
                s16x8 bVh = ldfrag((const char*)Vh, nj * 16 + (lane & 15), ks, lane);
                s16x8 bVl = ldfrag((const char*)Vl, nj * 16 + (lane & 15), ks, lane);
                acc_o[nj] = mfma16(aPl, bVh, acc_o[nj]);
                acc_o[nj] = mfma16(aPh, bVl, acc_o[nj]);
                acc_o[nj] = mfma16(aPh, bVh, acc_o[nj]);
            }
        }
    }

    if (partial) {
        // write unnormalized fp32 partial + per-row (m, l)
        float* pOt = pO + (size_t)bi * 4096;
#pragma unroll
        for (int r = 0; r < 4; r++) {
            int row = wv * 16 + (lane >> 4) * 4 + r;
#pragma unroll
            for (int nj = 0; nj < 4; nj++) {
                int col = nj * 16 + (lane & 15);
                pOt[row * 64 + col] = acc_o[nj][r];
            }
            if ((lane & 15) == 0) {
                pM[bi * 64 + row] = m_run[r];
                pL[bi * 64 + row] = l_run[r];
            }
        }
    } else {
#pragma unroll
        for (int r = 0; r < 4; r++) {
            int row_glob = q0 + wv * 16 + (lane >> 4) * 4 + r;
            float inv = 1.f / l_run[r];
#pragma unroll
            for (int nj = 0; nj < 4; nj++) {
                int dv = nj * 16 + (lane & 15);
                size_t idx = (size_t)(b * SEQ + row_glob) * (NH * HD) + h * HD + dv;
                float v = acc_o[nj][r] * inv;
                u16 hh = f2bf(v);
                outh[idx] = hh;
                outl[idx] = f2bf(v - bf2f(hh));
            }
        }
    }
}

// ---------------------------------------------------------------- flash-merge of heavy-tile halves
__global__ __launch_bounds__(256) void attn_combine(const float* __restrict__ pO,
    const float* __restrict__ pM, const float* __restrict__ pL,
    u16* __restrict__ outh, u16* __restrict__ outl)
{
    int t = blockIdx.x;                       // 0..255 heavy tiles
    int b = t >> 7, h = (t >> 3) & 15, qt = 15 - (t & 7);
    int q0 = qt * 64;
    int tid = threadIdx.x;
    int row = tid >> 2, cg = (tid & 3) * 16;
    int s0 = 2 * t, s1 = 2 * t + 1;
    float m0 = pM[s0 * 64 + row], l0 = pL[s0 * 64 + row];
    float m1 = pM[s1 * 64 + row], l1 = pL[s1 * 64 + row];
    float m = fmaxf(m0, m1);
    float c0 = __expf(m0 - m), c1 = __expf(m1 - m);
    float inv = 1.f / (l0 * c0 + l1 * c1);
    const float* O0 = pO + ((size_t)s0 * 64 + row) * 64 + cg;
    const float* O1 = pO + ((size_t)s1 * 64 + row) * 64 + cg;
    size_t ob = (size_t)(b * SEQ + q0 + row) * (NH * HD) + h * HD + cg;
#pragma unroll
    for (int j = 0; j < 16; j++) {
        float v = (O0[j] * c0 + O1[j] * c1) * inv;
        u16 hh = f2bf(v);
        outh[ob + j] = hh;
        outl[ob + j] = f2bf(v - bf2f(hh));
    }
}

// ---------------------------------------------------------------- MoE gate/up v3: 64-token tiles, 4 blocks/CU
__global__ __launch_bounds__(256, 4) void moe_gateup3(const u16* __restrict__ xb,
    const u16* __restrict__ wgb, const u16* __restrict__ wub,
    const int* __restrict__ assign_token, const int* __restrict__ offs,
    const int* __restrict__ counts, u16* __restrict__ hbufb)
{
    int e = blockIdx.z;
    int cnt = counts[e];
    int t0 = blockIdx.y * 64;
    if (t0 >= cnt) return;
    int base = offs[e];
    int h0 = blockIdx.x * 64;
    __shared__ __align__(16) u16 As[64 * 64];
    __shared__ __align__(16) u16 Gs[64 * 64];
    __shared__ __align__(16) u16 Us[64 * 64];
    __shared__ int toks[64];
    int tid = threadIdx.x;
    if (tid < 64) {
        int a = t0 + tid;
        toks[tid] = (a < cnt) ? assign_token[base + a] : 0;
    }
    __syncthreads();
    int lane = tid & 63, wv = tid >> 6;
    int wm = wv >> 1, wn = wv & 1;
    int sr = lane >> 3, sc = lane & 7;

    int tokr[2];
#pragma unroll
    for (int i = 0; i < 2; i++) tokr[i] = toks[wv * 16 + i * 8 + sr];

    const u16* wge = wgb + (size_t)e * HID * DIMM;
    const u16* wue = wub + (size_t)e * HID * DIMM;

    f32x4 accg[2][2], accu[2][2];
#pragma unroll
    for (int i = 0; i < 2; i++)
#pragma unroll
        for (int j = 0; j < 2; j++) { accg[i][j] = f32x4{0,0,0,0}; accu[i][j] = f32x4{0,0,0,0}; }

    const int NT = DIMM / 64;   // 16
    int bid = blockIdx.x + gridDim.x * (blockIdx.y + gridDim.y * blockIdx.z);
    int ph = (bid * 5) & (NT - 1);

    for (int tt = 0; tt < NT; ++tt) {
        int k0 = ((tt + ph) & (NT - 1)) << 6;
#pragma unroll
        for (int i = 0; i < 2; i++) {
            int row = wv * 16 + i * 8 + sr;
            int c = sc ^ (row & 7);
            gload16(xb + (size_t)tokr[i] * DIMM + k0 + c * 8, (void*)(As + (wv * 2 + i) * 512));
            gload16(wge + (size_t)(h0 + row) * DIMM + k0 + c * 8, (void*)(Gs + (wv * 2 + i) * 512));
            gload16(wue + (size_t)(h0 + row) * DIMM + k0 + c * 8, (void*)(Us + (wv * 2 + i) * 512));
        }
        __syncthreads();
#pragma unroll
        for (int ks = 0; ks < 2; ++ks) {
            s16x8 af[2], gf[2], uf[2];
#pragma unroll
            for (int mi = 0; mi < 2; mi++)
                af[mi] = ldfrag((const char*)As, wm * 32 + mi * 16 + (lane & 15), ks, lane);
#pragma unroll
            for (int nj = 0; nj < 2; nj++) {
                int row = wn * 32 + nj * 16 + (lane & 15);
                gf[nj] = ldfrag((const char*)Gs, row, ks, lane);
                uf[nj] = ldfrag((const char*)Us, row, ks, lane);
            }
#pragma unroll
            for (int mi = 0; mi < 2; mi++)
#pragma unroll
                for (int nj = 0; nj < 2; nj++) {
                    accg[mi][nj] = mfma16(af[mi], gf[nj], accg[mi][nj]);
                    accu[mi][nj] = mfma16(af[mi], uf[nj], accu[mi][nj]);
                }
        }
        __syncthreads();
    }
#pragma unroll
    for (int mi = 0; mi < 2; mi++)
#pragma unroll
        for (int nj = 0; nj < 2; nj++)
#pragma unroll
            for (int r = 0; r < 4; r++) {
                int row = wm * 32 + mi * 16 + (lane >> 4) * 4 + r;
                if (t0 + row < cnt) {
                    int col = wn * 32 + nj * 16 + (lane & 15);
                    float g = accg[mi][nj][r], u = accu[mi][nj][r];
                    float hh = (g / (1.f + __expf(-g))) * u;
                    hbufb[(size_t)(base + t0 + row) * HID + h0 + col] = f2bf(hh);
                }
            }
}

// ---------------------------------------------------------------- MoE down v8: 128x128, XCD-local remap + K-split x4
// e = bid&7 (expert -> XCD), x = (bid>>3)&7, ks = (bid>>6)&3 (K quarter), y = bid>>8.
// atomicAdd epilogue makes K-partials exact. Working blocks = bid < 4*256 contiguous -> 4/CU.
// All sharing strides (y:256, x:8, ks:64) are 0 mod 8 -> XCD-local L2 reuse preserved.
__global__ __launch_bounds__(256) void moe_down8(const u16* __restrict__ hbufb,
    const u16* __restrict__ wdb, const int* __restrict__ assign_token,
    const float* __restrict__ assign_w, const int* __restrict__ offs,
    const int* __restrict__ counts, float* __restrict__ out)
{
    int bid = blockIdx.x;
    int e = bid & 7;
    int x = (bid >> 3) & 7;
    int kslice = (bid >> 6) & 3;
    int y = bid >> 8;
    int cnt = counts[e];
    int t0 = y * 128;
    if (t0 >= cnt) return;
    int base = offs[e];
    int d0 = x * 128;
    int kbase = kslice * (HID / 4);      // 0, 512, 1024, 1536
    __shared__ __align__(16) u16 As[128 * 64];
    __shared__ __align__(16) u16 Bs[128 * 64];
    __shared__ int toks[128];
    __shared__ float rw_[128];
    int tid = threadIdx.x;
    if (tid < 128) {
        int a = t0 + tid;
        toks[tid] = (a < cnt) ? assign_token[base + a] : 0;
        rw_[tid] = (a < cnt) ? assign_w[base + a] : 0.f;
    }
    __syncthreads();
    int lane = tid & 63, wv = tid >> 6;
    int wm = wv >> 1, wn = wv & 1;
    int sr = lane >> 3, sc = lane & 7;

    const u16* wde = wdb + (size_t)e * DIMM * HID;

    f32x4 acc[4][4];
#pragma unroll
    for (int i = 0; i < 4; i++)
#pragma unroll
        for (int j = 0; j < 4; j++) acc[i][j] = f32x4{0,0,0,0};

    const int NT = HID / 256;   // 8 per K-quarter
    int ph = (bid * 5) & (NT - 1);

    for (int tt = 0; tt < NT; ++tt) {
        int k0 = kbase + (((tt + ph) & (NT - 1)) << 6);
#pragma unroll
        for (int i = 0; i < 4; i++) {
            int row = wv * 32 + i * 8 + sr;
            int c = sc ^ (row & 7);
            gload16(hbufb + (size_t)(base + t0 + row) * HID + k0 + c * 8, (void*)(As + (wv * 4 + i) * 512));
            gload16(wde + (size_t)(d0 + row) * HID + k0 + c * 8, (void*)(Bs + (wv * 4 + i) * 512));
        }
        __syncthreads();
#pragma unroll
        for (int ks = 0; ks < 2; ++ks) {
            s16x8 af[4];
#pragma unroll
            for (int mi = 0; mi < 4; mi++)
                af[mi] = ldfrag((const char*)As, wm * 64 + mi * 16 + (lane & 15), ks, lane);
#pragma unroll
            for (int nj = 0; nj < 4; nj++) {
                s16x8 bf = ldfrag((const char*)Bs, wn * 64 + nj * 16 + (lane & 15), ks, lane);
#pragma unroll
                for (int mi = 0; mi < 4; mi++)
                    acc[mi][nj] = mfma16(af[mi], bf, acc[mi][nj]);
            }
        }
        __syncthreads();
    }
#pragma unroll
    for (int mi = 0; mi < 4; mi++)
#pragma unroll
        for (int r = 0; r < 4; r++) {
            int row = wm * 64 + mi * 16 + (lane >> 4) * 4 + r;
            if (t0 + row < cnt) {
                int tok = toks[row];
                float w = rw_[row];
#pragma unroll
                for (int nj = 0; nj < 4; nj++) {
                    int col = d0 + wn * 64 + nj * 16 + (lane & 15);
                    atomicAdd(&out[(size_t)tok * DIMM + col], acc[mi][nj][r] * w);
                }
            }
        }
}

// ---------------------------------------------------------------- launch
extern "C" void kernel_launch(void* const* d_in, const int* in_sizes, int n_in,
                              void* d_out, int out_size, void* d_ws, size_t ws_size,
                              hipStream_t stream)
{
    const float* x      = (const float*)d_in[0];
    const float* cs     = (const float*)d_in[1];
    const float* sn     = (const float*)d_in[2];
    const float* w_na   = (const float*)d_in[3];
    const float* wq     = (const float*)d_in[4];
    const float* wk     = (const float*)d_in[5];
    const float* wv     = (const float*)d_in[6];
    const float* wo     = (const float*)d_in[7];
    const float* w_nf   = (const float*)d_in[8];
    const float* rw     = (const float*)d_in[9];
    const float* rb     = (const float*)d_in[10];
    const float* wg     = (const float*)d_in[11];
    const float* wu     = (const float*)d_in[12];
    const float* wd     = (const float*)d_in[13];
    float* out = (float*)d_out;

    const size_t F = 1024 * 1024;
    float* wsf = (float*)d_ws;

    // layout (float units):
    float* qkvb = wsf;                            // 0..3F     [2048][1536] fp32 (dead after prep2 -> attn partials)
    float* tail = wsf + 3 * F;                    // 3..3.5F   routing scratch
    u16* qsh    = (u16*)(wsf + 3 * F + F / 2);    // 3.5..4.5F [2048][1024]
    u16* qsl    = (u16*)(wsf + 4 * F + F / 2);    // 4.5..5.5F
    u16* ksh    = (u16*)(wsf + 5 * F + F / 2);    // 5.5..5.75F [2048][256]
    u16* ksl    = (u16*)(wsf + 5 * F + 3 * F / 4);// 5.75..6F
    u16* vth    = (u16*)(wsf + 6 * F);            // 6..6.25F  [256][2048]
    u16* vtl    = (u16*)(wsf + 6 * F + F / 4);    // 6.25..6.5F
    u16* xn2b   = (u16*)(wsf + 6 * F + F / 2);    // 6.5..7.5F [2048][1024]
    u16* hbufb  = (u16*)(wsf + 7 * F + F / 2);    // 7.5..11.5F (MoE h, 8M u16)
    u16* xnh    = (u16*)(wsf + 7 * F + F / 2);    //   alias 7.5..8.5F (dead before moe)
    u16* xnl    = (u16*)(wsf + 8 * F + F / 2);    //   alias 8.5..9.5F
    u16* attnh  = (u16*)(wsf + 9 * F + F / 2);    //   alias 9.5..10.5F
    u16* attnl  = (u16*)(wsf + 10 * F + F / 2);   //   alias 10.5..11.5F
    u16* wgb    = (u16*)(wsf + 11 * F + F / 2);   // 11.5..19.5F
    u16* wub    = (u16*)(wsf + 19 * F + F / 2);   // 19.5..27.5F
    u16* wdb    = (u16*)(wsf + 27 * F + F / 2);   // 27.5..35.5F
    u16* wqkvoh = (u16*)(wsf + 35 * F + F / 2);   // 35.5..36.75F
    u16* wqkvol = (u16*)(wsf + 36 * F + 3 * F / 4); // 36.75..38F

    int*   top_idx      = (int*)tail;                     // 4096
    float* top_w        = tail + 4096;                    // 4096
    int*   counts       = (int*)(tail + 8192);            // 8
    int*   offs         = (int*)(tail + 8192) + 8;        // 8
    int*   assign_token = (int*)(tail + 8192) + 32;       // 4096
    float* assign_w     = tail + 8192 + 32 + 4096;        // 4096

    // attn partials aliased over dead qkvb: 512 x (64x64 fp32) + m/l
    float* pO = qkvb;                      // 512*4096 = 2,097,152 floats
    float* pM = qkvb + 2097152;            // 32768
    float* pL = qkvb + 2097152 + 32768;    // 32768  (total 2.16M < 3M)

    const int CV1 = 5242880;   // 5M float4    (qkv window, -0.5M rebalance)
    const int CV2 = 8912896;   // 8.5M         (attn window: 3.5M)
    const int CV3 = 12582912;  // 12M          (o window: 3.5M)

    // 1. qkvo weight split-cvt + rmsnorm(attn)  [merged]
    prep1<<<3072, 256, 0, stream>>>(wq, wk, wv, wo, wqkvoh, wqkvol, x, w_na, xnh, xnl);
    // 2. fused qkv projection + MoE cvt chunk 1  [384 gemm + 1280 cvt blocks]
    gemm_cvt<<<384 + 1280, 256, 0, stream>>>(xnh, xnl, wqkvoh, wqkvol,
                                             qkvb, nullptr, N_TOK, QKVW, DIMM, QKVW,
                                             QKVW / 64, 16,
                                             wg, wu, wd, wgb, wub, wdb, 0, CV1, 1280);
    // 3. RoPE (q+k) + V transpose  [merged]
    prep2<<<5248, 256, 0, stream>>>(qkvb, cs, sn, qsh, qsl, ksh, ksl, vth, vtl);
    // 4. attention (kt-split heavy tiles) + MoE cvt chunk 2  [768 attn + 1024 cvt blocks]
    attn_cvt<<<1792, 256, 0, stream>>>(qsh, qsl, ksh, ksl, vth, vtl, attnh, attnl,
                                       pO, pM, pL,
                                       wg, wu, wd, wgb, wub, wdb, CV1, CV2, 1024);
    // 4.5 flash-merge of heavy-tile halves
    attn_combine<<<256, 256, 0, stream>>>(pO, pM, pL, attnh, attnl);
    // 5. output projection + residual + MoE cvt chunk 3  [256 gemm + 768 cvt blocks]
    gemm_cvt<<<256 + 768, 256, 0, stream>>>(attnh, attnl,
                                            wqkvoh + (size_t)1536 * 1024, wqkvol + (size_t)1536 * 1024,
                                            out, x, N_TOK, DIMM, NH * HD, DIMM,
                                            DIMM / 64, 16,
                                            wg, wu, wd, wgb, wub, wdb, CV2, CV3, 768);
    // 6. rmsnorm (ffn) + router logits + top2  [fused]
    rmsnorm_router<<<N_TOK, 256, 0, stream>>>(out, w_nf, rw, rb, xn2b, top_idx, top_w);
    // 7. routing build
    route_build<<<1, 256, 0, stream>>>(top_idx, top_w, counts, offs, assign_token, assign_w);
    // 8-9. MoE (gateup unchanged; down K-split x4 for 4 working blocks/CU)
    moe_gateup3<<<dim3(HID / 64, 32, NEXP), 256, 0, stream>>>(xn2b, wgb, wub, assign_token, offs, counts, hbufb);
    moe_down8<<<4096, 256, 0, stream>>>(hbufb, wdb, assign_token, assign_w, offs, counts, out);
}

// Round 31
// 278.153 us; speedup vs baseline: 1.0663x; 1.0663x over previous
//
#include <hip/hip_runtime.h>
#include <math.h>

#define N_TOK   2048      // B*T
#define SEQ     1024
#define DIMM    1024
#define NH      16
#define NKV     4
#define HD      64
#define HID     2048
#define NEXP    8
#define QKVW    1536      // fused q|k|v row width

typedef __attribute__((ext_vector_type(4))) float f32x4;
typedef __attribute__((ext_vector_type(8))) short s16x8;
typedef unsigned short u16;

__device__ __forceinline__ u16 f2bf(float f) {
    union { float f; unsigned u; } v; v.f = f;
    unsigned r = v.u + 0x7fffu + ((v.u >> 16) & 1u);
    return (u16)(r >> 16);
}
__device__ __forceinline__ float bf2f(u16 h) {
    union { unsigned u; float f; } v; v.u = ((unsigned)h) << 16;
    return v.f;
}

__device__ __forceinline__ f32x4 mfma16(s16x8 a, s16x8 b, f32x4 c) {
    return __builtin_amdgcn_mfma_f32_16x16x32_bf16(a, b, c, 0, 0, 0);
}

// LDS tile row stride = 64 bf16 = 128 B; XOR-swizzle 16B slot with row&7 (T2)
__device__ __forceinline__ int lds_byte(int row, int byte_in_row, int swz_key) {
    return row * 128 + (byte_in_row ^ ((swz_key & 7) << 4));
}

// load a 16B MFMA fragment (8 bf16) for logical row `row`, k-slice ks (0/1)
__device__ __forceinline__ s16x8 ldfrag(const char* base, int row, int ks, int lane) {
    int b = lds_byte(row, ks * 64 + ((lane >> 4) * 16), row);
    return *(const s16x8*)(base + b);
}

// async 16B global -> LDS (wave-uniform LDS base + lane*16)
__device__ __forceinline__ void gload16(const void* g, void* l) {
    __builtin_amdgcn_global_load_lds(
        (const __attribute__((address_space(1))) void*)g,
        (__attribute__((address_space(3))) void*)l, 16, 0, 0);
}

// coalesced ILP-4 cvt of chunk [cvt_base, cvt_end) of the 12M-float4 wg|wu|wd space
__device__ __forceinline__ void cvt_chunk(int cb, int ncvt, int cvt_base, int cvt_end,
    const float* __restrict__ wg, const float* __restrict__ wu, const float* __restrict__ wd,
    u16* __restrict__ wgb, u16* __restrict__ wub, u16* __restrict__ wdb, int tid)
{
    const int n4 = 4 << 20;   // 4M float4 per tensor
    int i = cvt_base + cb * 1024 + tid;
    int stride = ncvt * 1024;
    for (; i < cvt_end; i += stride) {
        int seg = i >> 22;                // 1024-block never crosses a 4M segment
        int j = i & (n4 - 1);
        const f32x4* in = (const f32x4*)((seg == 0) ? wg : (seg == 1) ? wu : wd);
        ushort4* out = (ushort4*)((seg == 0) ? wgb : (seg == 1) ? wub : wdb);
        f32x4 v0 = __builtin_nontemporal_load(in + j);
        f32x4 v1 = __builtin_nontemporal_load(in + j + 256);
        f32x4 v2 = __builtin_nontemporal_load(in + j + 512);
        f32x4 v3 = __builtin_nontemporal_load(in + j + 768);
        ushort4 o0, o1, o2, o3;
        o0.x = f2bf(v0[0]); o0.y = f2bf(v0[1]); o0.z = f2bf(v0[2]); o0.w = f2bf(v0[3]);
        o1.x = f2bf(v1[0]); o1.y = f2bf(v1[1]); o1.z = f2bf(v1[2]); o1.w = f2bf(v1[3]);
        o2.x = f2bf(v2[0]); o2.y = f2bf(v2[1]); o2.z = f2bf(v2[2]); o2.w = f2bf(v2[3]);
        o3.x = f2bf(v3[0]); o3.y = f2bf(v3[1]); o3.z = f2bf(v3[2]); o3.w = f2bf(v3[3]);
        out[j]       = o0;
        out[j + 256] = o1;
        out[j + 512] = o2;
        out[j + 768] = o3;
    }
}

// ---------------------------------------------------------------- prep1: qkvo split-cvt + rmsnorm(attn)
__global__ __launch_bounds__(256) void prep1(const float* __restrict__ wq,
    const float* __restrict__ wk, const float* __restrict__ wv, const float* __restrict__ wo,
    u16* __restrict__ hi, u16* __restrict__ lo,
    const float* __restrict__ x, const float* __restrict__ w_na,
    u16* __restrict__ oh, u16* __restrict__ ol)
{
    if (blockIdx.x < 1024) {
        int i = blockIdx.x * 256 + threadIdx.x;
        int stride = 1024 * 256;
        for (; i < 655360; i += stride) {
            const float* in; int j;
            if (i < 262144)      { in = wq; j = i; }
            else if (i < 327680) { in = wk; j = i - 262144; }
            else if (i < 393216) { in = wv; j = i - 327680; }
            else                 { in = wo; j = i - 393216; }
            f32x4 v = __builtin_nontemporal_load((const f32x4*)in + j);
            ushort4 h, l;
            h.x = f2bf(v[0]); h.y = f2bf(v[1]); h.z = f2bf(v[2]); h.w = f2bf(v[3]);
            l.x = f2bf(v[0] - bf2f(h.x)); l.y = f2bf(v[1] - bf2f(h.y));
            l.z = f2bf(v[2] - bf2f(h.z)); l.w = f2bf(v[3] - bf2f(h.w));
            reinterpret_cast<ushort4*>(hi)[i] = h;
            reinterpret_cast<ushort4*>(lo)[i] = l;
        }
    } else {
        int row = blockIdx.x - 1024;
        const float4* xr = reinterpret_cast<const float4*>(x + (size_t)row * DIMM);
        const float4* wr = reinterpret_cast<const float4*>(w_na);
        float4 v = xr[threadIdx.x];
        float ss = v.x*v.x + v.y*v.y + v.z*v.z + v.w*v.w;
#pragma unroll
        for (int off = 32; off; off >>= 1) ss += __shfl_xor(ss, off);
        __shared__ float red[4];
        int wid = threadIdx.x >> 6, lane = threadIdx.x & 63;
        if (lane == 0) red[wid] = ss;
        __syncthreads();
        float tot = red[0] + red[1] + red[2] + red[3];
        float inv = rsqrtf(tot * (1.0f/DIMM) + 1e-6f);
        float4 ww = wr[threadIdx.x];
        float4 o;
        o.x = ww.x * v.x * inv;
        o.y = ww.y * v.y * inv;
        o.z = ww.z * v.z * inv;
        o.w = ww.w * v.w * inv;
        ushort4 h, l;
        h.x = f2bf(o.x); h.y = f2bf(o.y); h.z = f2bf(o.z); h.w = f2bf(o.w);
        l.x = f2bf(o.x - bf2f(h.x)); l.y = f2bf(o.y - bf2f(h.y));
        l.z = f2bf(o.z - bf2f(h.z)); l.w = f2bf(o.w - bf2f(h.w));
        reinterpret_cast<ushort4*>(oh + (size_t)row * DIMM)[threadIdx.x] = h;
        reinterpret_cast<ushort4*>(ol + (size_t)row * DIMM)[threadIdx.x] = l;
    }
}

// ---------------------------------------------------------------- rmsnorm + router logits + top2 (all fused)
__global__ __launch_bounds__(256) void rmsnorm_router(const float* __restrict__ x,
    const float* __restrict__ w, const float* __restrict__ rw, const float* __restrict__ rb,
    u16* __restrict__ outb, int* __restrict__ top_idx, float* __restrict__ top_w)
{
    int row = blockIdx.x;
    int tid = threadIdx.x;
    int wid = tid >> 6, lane = tid & 63;
    const float4* xr = reinterpret_cast<const float4*>(x + (size_t)row * DIMM);
    const float4* wr = reinterpret_cast<const float4*>(w);
    float4 v = xr[tid];
    float ss = v.x*v.x + v.y*v.y + v.z*v.z + v.w*v.w;
#pragma unroll
    for (int off = 32; off; off >>= 1) ss += __shfl_xor(ss, off);
    __shared__ float red[4];
    __shared__ float lred[4][NEXP];
    if (lane == 0) red[wid] = ss;
    __syncthreads();
    float tot = red[0] + red[1] + red[2] + red[3];
    float inv = rsqrtf(tot * (1.0f/DIMM) + 1e-6f);
    float4 ww = wr[tid];
    float4 o;
    o.x = ww.x * v.x * inv;
    o.y = ww.y * v.y * inv;
    o.z = ww.z * v.z * inv;
    o.w = ww.w * v.w * inv;
    ushort4 ob;
    ob.x = f2bf(o.x); ob.y = f2bf(o.y); ob.z = f2bf(o.z); ob.w = f2bf(o.w);
    reinterpret_cast<ushort4*>(outb + (size_t)row * DIMM)[tid] = ob;
    float acc[NEXP];
#pragma unroll
    for (int e = 0; e < NEXP; e++) {
        float4 r4 = reinterpret_cast<const float4*>(rw + (size_t)e * DIMM)[tid];
        acc[e] = o.x * r4.x + o.y * r4.y + o.z * r4.z + o.w * r4.w;
    }
#pragma unroll
    for (int e = 0; e < NEXP; e++) {
        float p = acc[e];
#pragma unroll
        for (int off = 32; off; off >>= 1) p += __shfl_xor(p, off);
        acc[e] = p;
    }
    if (lane == 0)
#pragma unroll
        for (int e = 0; e < NEXP; e++) lred[wid][e] = acc[e];
    __syncthreads();
    if (tid == 0) {
        float lg[NEXP];
#pragma unroll
        for (int e = 0; e < NEXP; e++)
            lg[e] = lred[0][e] + lred[1][e] + lred[2][e] + lred[3][e] + rb[e];
        float m = lg[0];
#pragma unroll
        for (int e = 1; e < NEXP; e++) m = fmaxf(m, lg[e]);
        float pe[NEXP], s = 0.f;
#pragma unroll
        for (int e = 0; e < NEXP; e++) { pe[e] = __expf(lg[e] - m); s += pe[e]; }
        int i1 = 0; float v1 = pe[0];
#pragma unroll
        for (int e = 1; e < NEXP; e++) if (pe[e] > v1) { v1 = pe[e]; i1 = e; }
        int i2 = -1; float v2 = -1.f;
#pragma unroll
        for (int e = 0; e < NEXP; e++) if (e != i1 && pe[e] > v2) { v2 = pe[e]; i2 = e; }
        v1 /= s; v2 /= s;
        float den = v1 + v2 + 1e-9f;
        top_idx[2 * row] = i1; top_idx[2 * row + 1] = i2;
        top_w[2 * row] = v1 / den; top_w[2 * row + 1] = v2 / den;
    }
}

// ---------------------------------------------------------------- single-block routing build
__global__ __launch_bounds__(256) void route_build(const int* __restrict__ top_idx,
    const float* __restrict__ top_w, int* __restrict__ counts, int* __restrict__ offs,
    int* __restrict__ assign_token, float* __restrict__ assign_w)
{
    __shared__ int lcnt[NEXP], loff[NEXP], lpos[NEXP];
    int tid = threadIdx.x;
    if (tid < NEXP) { lcnt[tid] = 0; lpos[tid] = 0; }
    __syncthreads();
    for (int i = tid; i < 2 * N_TOK; i += 256)
        atomicAdd(&lcnt[top_idx[i]], 1);
    __syncthreads();
    if (tid == 0) {
        int s = 0;
        for (int e = 0; e < NEXP; e++) { loff[e] = s; s += lcnt[e]; }
    }
    __syncthreads();
    if (tid < NEXP) { counts[tid] = lcnt[tid]; offs[tid] = loff[tid]; }
    for (int i = tid; i < 2 * N_TOK; i += 256) {
        int e = top_idx[i];
        int p = atomicAdd(&lpos[e], 1);
        int r = loff[e] + p;
        assign_token[r] = i >> 1;
        assign_w[r] = top_w[i];
    }
}

// ---------------------------------------------------------------- split-bf16 GEMM + MoE cvt tail (1-D grid)
__global__ __launch_bounds__(256) void gemm_cvt(const u16* __restrict__ Ah_,
    const u16* __restrict__ Al_, const u16* __restrict__ Bh_, const u16* __restrict__ Bl_,
    float* __restrict__ C, const float* __restrict__ R, int M, int N, int K, int ldc,
    int gx, int gy,
    const float* __restrict__ wg, const float* __restrict__ wu, const float* __restrict__ wd,
    u16* __restrict__ wgb, u16* __restrict__ wub, u16* __restrict__ wdb,
    int cvt_base, int cvt_end, int ncvt)
{
    int blk = blockIdx.x;
    if (blk >= gx * gy) {
        cvt_chunk(blk - gx * gy, ncvt, cvt_base, cvt_end, wg, wu, wd, wgb, wub, wdb, threadIdx.x);
        return;
    }
    __shared__ __align__(16) u16 Ah[128 * 64], Al[128 * 64];
    __shared__ __align__(16) u16 Bh[64 * 64],  Bl[64 * 64];
    int tid = threadIdx.x;
    int m0 = (blk / gx) * 128, n0 = (blk % gx) * 64;
    int lane = tid & 63, wv = tid >> 6;
    int wm = wv >> 1, wn = wv & 1;
    int sr = lane >> 3, sc = lane & 7;

    f32x4 acc[4][2];
#pragma unroll
    for (int i = 0; i < 4; i++)
#pragma unroll
        for (int j = 0; j < 2; j++) acc[i][j] = f32x4{0.f, 0.f, 0.f, 0.f};

    const int NT = K >> 6;
    int ph = (blk * 5) & (NT - 1);

    for (int tt = 0; tt < NT; ++tt) {
        int k0 = ((tt + ph) & (NT - 1)) << 6;
#pragma unroll
        for (int i = 0; i < 4; i++) {
            int row = wv * 32 + i * 8 + sr;
            int c = sc ^ (row & 7);
            size_t g = (size_t)(m0 + row) * K + k0 + c * 8;
            gload16(Ah_ + g, (void*)(Ah + (wv * 4 + i) * 512));
            gload16(Al_ + g, (void*)(Al + (wv * 4 + i) * 512));
        }
#pragma unroll
        for (int i = 0; i < 2; i++) {
            int row = wv * 16 + i * 8 + sr;
            int c = sc ^ (row & 7);
            size_t g = (size_t)(n0 + row) * K + k0 + c * 8;
            gload16(Bh_ + g, (void*)(Bh + (wv * 2 + i) * 512));
            gload16(Bl_ + g, (void*)(Bl + (wv * 2 + i) * 512));
        }
        __syncthreads();
#pragma unroll
        for (int ks = 0; ks < 2; ++ks) {
            s16x8 afh[4], afl[4], bfh[2], bfl[2];
#pragma unroll
            for (int mi = 0; mi < 4; mi++) {
                int row = wm * 64 + mi * 16 + (lane & 15);
                afh[mi] = ldfrag((const char*)Ah, row, ks, lane);
                afl[mi] = ldfrag((const char*)Al, row, ks, lane);
            }
#pragma unroll
            for (int nj = 0; nj < 2; nj++) {
                int row = wn * 32 + nj * 16 + (lane & 15);
                bfh[nj] = ldfrag((const char*)Bh, row, ks, lane);
                bfl[nj] = ldfrag((const char*)Bl, row, ks, lane);
            }
#pragma unroll
            for (int mi = 0; mi < 4; mi++)
#pragma unroll
                for (int nj = 0; nj < 2; nj++) {
                    acc[mi][nj] = mfma16(afl[mi], bfh[nj], acc[mi][nj]);
                    acc[mi][nj] = mfma16(afh[mi], bfl[nj], acc[mi][nj]);
                    acc[mi][nj] = mfma16(afh[mi], bfh[nj], acc[mi][nj]);
                }
        }
        __syncthreads();
    }
#pragma unroll
    for (int mi = 0; mi < 4; mi++)
#pragma unroll
        for (int nj = 0; nj < 2; nj++)
#pragma unroll
            for (int r = 0; r < 4; r++) {
                int m = m0 + wm * 64 + mi * 16 + (lane >> 4) * 4 + r;
                int n = n0 + wn * 32 + nj * 16 + (lane & 15);
                float v = acc[mi][nj][r];
                if (R) v += R[(size_t)m * ldc + n];
                C[(size_t)m * ldc + n] = v;
            }
}

// ---------------------------------------------------------------- prep2: RoPE(q,k) + V transpose (merged)
__global__ __launch_bounds__(256) void prep2(const float* __restrict__ qkvb,
    const float* __restrict__ cs, const float* __restrict__ sn,
    u16* __restrict__ qsh, u16* __restrict__ qsl,
    u16* __restrict__ ksh, u16* __restrict__ ksl,
    u16* __restrict__ vth, u16* __restrict__ vtl)
{
    const int ROPE_BLOCKS = (N_TOK * (NH + NKV) * 32) / 256;   // 5120
    if (blockIdx.x < ROPE_BLOCKS) {
        int gid = blockIdx.x * 256 + threadIdx.x;
        const int QTOT = N_TOK * NH * 32;
        int nheads, base_col, out_w;
        u16 *oh, *ol;
        if (gid < QTOT) {
            nheads = NH; base_col = 0; out_w = NH * HD; oh = qsh; ol = qsl;
        } else {
            gid -= QTOT;
            nheads = NKV; base_col = 1024; out_w = NKV * HD; oh = ksh; ol = ksl;
        }
        int i = gid & 31;
        int h = (gid >> 5) % nheads;
        int n = gid / (32 * nheads);
        int t = n & (SEQ - 1);
        const float* p = qkvb + (size_t)n * QKVW + base_col + h * HD + 2 * i;
        float xe = p[0], xo = p[1];
        float c = cs[t * 32 + i], s = sn[t * 32 + i];
        float re = xe * c - xo * s;
        float ro = xe * s + xo * c;
        size_t o = (size_t)n * out_w + h * HD + 2 * i;
        u16 reh = f2bf(re), roh = f2bf(ro);
        oh[o] = reh;     oh[o + 1] = roh;
        ol[o] = f2bf(re - bf2f(reh));
        ol[o + 1] = f2bf(ro - bf2f(roh));
    } else {
        __shared__ float t[64][65];
        int r = blockIdx.x - ROPE_BLOCKS;       // 128 blocks: 32 x 4
        int bx = r & 31;
        int by = r >> 5;
        int tid = threadIdx.x;
        int c4 = tid & 15, r0 = tid >> 4;
#pragma unroll
        for (int i = 0; i < 4; i++) {
            int row = r0 + i * 16;
            float4 vv = *(const float4*)(qkvb + (size_t)(bx * 64 + row) * QKVW + 1280 + by * 64 + c4 * 4);
            t[c4 * 4 + 0][row] = vv.x;
            t[c4 * 4 + 1][row] = vv.y;
            t[c4 * 4 + 2][row] = vv.z;
            t[c4 * 4 + 3][row] = vv.w;
        }
        __syncthreads();
#pragma unroll
        for (int i = 0; i < 4; i++) {
            int drow = r0 + i * 16;
            ushort4 hh, ll;
            float a = t[drow][c4 * 4 + 0], b = t[drow][c4 * 4 + 1];
            float c = t[drow][c4 * 4 + 2], d = t[drow][c4 * 4 + 3];
            hh.x = f2bf(a); hh.y = f2bf(b); hh.z = f2bf(c); hh.w = f2bf(d);
            ll.x = f2bf(a - bf2f(hh.x)); ll.y = f2bf(b - bf2f(hh.y));
            ll.z = f2bf(c - bf2f(hh.z)); ll.w = f2bf(d - bf2f(hh.w));
            size_t o = ((size_t)(by * 64 + drow) * N_TOK + bx * 64 + c4 * 4) >> 2;
            reinterpret_cast<ushort4*>(vth)[o] = hh;
            reinterpret_cast<ushort4*>(vtl)[o] = ll;
        }
    }
}

// ---------------------------------------------------------------- attention (kt-split for qt>=8) + MoE weight cvt
// blocks [0,512): heavy-tile halves (b,h,qt>=8)x2 -> fp32 partials (pO,pM,pL)
// blocks [512,768): light tiles (qt<8) -> direct split-bf16 output
// blocks [768,1792): cvt chunk
__global__ __launch_bounds__(256) void attn_cvt(const u16* __restrict__ qsh,
    const u16* __restrict__ qsl, const u16* __restrict__ ksh, const u16* __restrict__ ksl,
    const u16* __restrict__ vth, const u16* __restrict__ vtl,
    u16* __restrict__ outh, u16* __restrict__ outl,
    float* __restrict__ pO, float* __restrict__ pM, float* __restrict__ pL,
    const float* __restrict__ wg, const float* __restrict__ wu, const float* __restrict__ wd,
    u16* __restrict__ wgb, u16* __restrict__ wub, u16* __restrict__ wdb,
    int cvt_base, int cvt_end, int ncvt)
{
    if (blockIdx.x >= 768) {
        cvt_chunk(blockIdx.x - 768, ncvt, cvt_base, cvt_end, wg, wu, wd, wgb, wub, wdb, threadIdx.x);
        return;
    }
    int bi = blockIdx.x;
    int b, h, qt, kt_lo, kt_hi;
    bool partial;
    if (bi < 512) {                       // heavy halves
        int part = bi & 1;
        int t = bi >> 1;                  // 0..255
        b = t >> 7; h = (t >> 3) & 15; qt = 15 - (t & 7);   // qt in 8..15
        int half = (qt + 1) >> 1;
        kt_lo = part ? half : 0;
        kt_hi = part ? qt : half - 1;
        partial = true;
    } else {                              // light tiles
        int idx = bi - 512;               // 0..255
        b = idx >> 7; h = (idx >> 3) & 15; qt = 7 - (idx & 7);
        kt_lo = 0; kt_hi = qt;
        partial = false;
    }
    int kvh = h >> 2;
    int tid = threadIdx.x;
    int lane = tid & 63, wv = tid >> 6;
    int q0 = qt * 64;
    int sr = lane >> 3, sc = lane & 7;

    // Q buffers are consumed into registers before the K-loop, then reused as P buffers.
    __shared__ __align__(16) u16 Qh[64 * 64], Ql[64 * 64];   // later: Ph, Pl (per-wave 2KB chunks)
    __shared__ __align__(16) u16 Kh[64 * 64], Kl[64 * 64];
    __shared__ __align__(16) u16 Vh[64 * 64], Vl[64 * 64];

#pragma unroll
    for (int i = 0; i < 2; i++) {
        int row = wv * 16 + i * 8 + sr;
        int c = sc ^ (row & 7);
        size_t g = (size_t)(b * SEQ + q0 + row) * (NH * HD) + h * HD + c * 8;
        gload16(qsh + g, (void*)(Qh + (wv * 2 + i) * 512));
        gload16(qsl + g, (void*)(Ql + (wv * 2 + i) * 512));
    }
    __syncthreads();

    s16x8 aQh[2], aQl[2];
#pragma unroll
    for (int ks = 0; ks < 2; ks++) {
        aQh[ks] = ldfrag((const char*)Qh, wv * 16 + (lane & 15), ks, lane);
        aQl[ks] = ldfrag((const char*)Ql, wv * 16 + (lane & 15), ks, lane);
    }

    float m_run[4], l_run[4];
    f32x4 acc_o[4];
#pragma unroll
    for (int r = 0; r < 4; r++) { m_run[r] = -1e30f; l_run[r] = 0.f; }
#pragma unroll
    for (int nj = 0; nj < 4; nj++) acc_o[nj] = f32x4{0.f, 0.f, 0.f, 0.f};

    for (int kt = kt_lo; kt <= kt_hi; kt++) {
        int kbase = kt * 64;
        __syncthreads();
#pragma unroll
        for (int i = 0; i < 2; i++) {
            int row = wv * 16 + i * 8 + sr;
            int c = sc ^ (row & 7);
            size_t gk = (size_t)(b * SEQ + kbase + row) * (NKV * HD) + kvh * HD + c * 8;
            size_t gv = (size_t)(kvh * HD + row) * N_TOK + b * SEQ + kbase + c * 8;
            gload16(ksh + gk, (void*)(Kh + (wv * 2 + i) * 512));
            gload16(ksl + gk, (void*)(Kl + (wv * 2 + i) * 512));
            gload16(vth + gv, (void*)(Vh + (wv * 2 + i) * 512));
            gload16(vtl + gv, (void*)(Vl + (wv * 2 + i) * 512));
        }
        __syncthreads();

        f32x4 sacc[4];
#pragma unroll
        for (int nj = 0; nj < 4; nj++) sacc[nj] = f32x4{0.f, 0.f, 0.f, 0.f};
#pragma unroll
        for (int ks = 0; ks < 2; ks++) {
#pragma unroll
            for (int nj = 0; nj < 4; nj++) {
                s16x8 bKh = ldfrag((const char*)Kh, nj * 16 + (lane & 15), ks, lane);
                s16x8 bKl = ldfrag((const char*)Kl, nj * 16 + (lane & 15), ks, lane);
                sacc[nj] = mfma16(aQl[ks], bKh, sacc[nj]);
                sacc[nj] = mfma16(aQh[ks], bKl, sacc[nj]);
                sacc[nj] = mfma16(aQh[ks], bKh, sacc[nj]);
            }
        }

        float sv[4][4];
#pragma unroll
        for (int nj = 0; nj < 4; nj++)
#pragma unroll
            for (int r = 0; r < 4; r++) {
                float s = sacc[nj][r] * 0.125f;
                if (kt == qt) {
                    int row_loc = wv * 16 + (lane >> 4) * 4 + r;
                    int col_loc = nj * 16 + (lane & 15);
                    if (col_loc > row_loc) s = -1e30f;
                }
                sv[nj][r] = s;
            }

        float p[4][4];
#pragma unroll
        for (int r = 0; r < 4; r++) {
            float mx = fmaxf(fmaxf(sv[0][r], sv[1][r]), fmaxf(sv[2][r], sv[3][r]));
            mx = fmaxf(mx, __shfl_xor(mx, 1));
            mx = fmaxf(mx, __shfl_xor(mx, 2));
            mx = fmaxf(mx, __shfl_xor(mx, 4));
            mx = fmaxf(mx, __shfl_xor(mx, 8));
            float m_new = fmaxf(m_run[r], mx);
            float corr = __expf(m_run[r] - m_new);
            float ps = 0.f;
#pragma unroll
            for (int nj = 0; nj < 4; nj++) {
                float pv = __expf(sv[nj][r] - m_new);
                p[nj][r] = pv;
                ps += pv;
            }
            ps += __shfl_xor(ps, 1);
            ps += __shfl_xor(ps, 2);
            ps += __shfl_xor(ps, 4);
            ps += __shfl_xor(ps, 8);
            l_run[r] = l_run[r] * corr + ps;
            m_run[r] = m_new;
#pragma unroll
            for (int nj = 0; nj < 4; nj++) acc_o[nj][r] *= corr;
        }

        // P (split) into per-wave 2KB chunks aliased over Qh/Ql
        char* phb = (char*)Qh + wv * 2048;
        char* plb = (char*)Ql + wv * 2048;
#pragma unroll
        for (int nj = 0; nj < 4; nj++)
#pragma unroll
            for (int r = 0; r < 4; r++) {
                int row = (lane >> 4) * 4 + r;
                int col = nj * 16 + (lane & 15);
                u16 hh = f2bf(p[nj][r]);
                u16 ll = f2bf(p[nj][r] - bf2f(hh));
                int byte = lds_byte(row, col * 2, row);
                *(u16*)(phb + byte) = hh;
                *(u16*)(plb + byte) = ll;
            }

#pragma unroll
        for (int ks = 0; ks < 2; ks++) {
            s16x8 aPh = ldfrag(phb, lane & 15, ks, lane);
            s16x8 aPl = ldfrag(plb, lane & 15, ks, lane);
#pragma unroll
            for (int nj = 0; nj < 4; nj++) {
                s16x8 bVh = ldfrag((const char*)Vh, nj * 16 + (lane & 15), ks, lane);
                s16x8 bVl = ldfrag((const char*)Vl, nj * 16 + (lane & 15), ks, lane);
                acc_o[nj] = mfma16(aPl, bVh, acc_o[nj]);
                acc_o[nj] = mfma16(aPh, bVl, acc_o[nj]);
                acc_o[nj] = mfma16(aPh, bVh, acc_o[nj]);
            }
        }
    }

    if (partial) {
        // write unnormalized fp32 partial + per-row (m, l)
        float* pOt = pO + (size_t)bi * 4096;
#pragma unroll
        for (int r = 0; r < 4; r++) {
            int row = wv * 16 + (lane >> 4) * 4 + r;
#pragma unroll
            for (int nj = 0; nj < 4; nj++) {
                int col = nj * 16 + (lane & 15);
                pOt[row * 64 + col] = acc_o[nj][r];
            }
            if ((lane & 15) == 0) {
                pM[bi * 64 + row] = m_run[r];
                pL[bi * 64 + row] = l_run[r];
            }
        }
    } else {
#pragma unroll
        for (int r = 0; r < 4; r++) {
            int row_glob = q0 + wv * 16 + (lane >> 4) * 4 + r;
            float inv = 1.f / l_run[r];
#pragma unroll
            for (int nj = 0; nj < 4; nj++) {
                int dv = nj * 16 + (lane & 15);
                size_t idx = (size_t)(b * SEQ + row_glob) * (NH * HD) + h * HD + dv;
                float v = acc_o[nj][r] * inv;
                u16 hh = f2bf(v);
                outh[idx] = hh;
                outl[idx] = f2bf(v - bf2f(hh));
            }
        }
    }
}

// ---------------------------------------------------------------- flash-merge of heavy-tile halves
__global__ __launch_bounds__(256) void attn_combine(const float* __restrict__ pO,
    const float* __restrict__ pM, const float* __restrict__ pL,
    u16* __restrict__ outh, u16* __restrict__ outl)
{
    int t = blockIdx.x;                       // 0..255 heavy tiles
    int b = t >> 7, h = (t >> 3) & 15, qt = 15 - (t & 7);
    int q0 = qt * 64;
    int tid = threadIdx.x;
    int row = tid >> 2, cg = (tid & 3) * 16;
    int s0 = 2 * t, s1 = 2 * t + 1;
    float m0 = pM[s0 * 64 + row], l0 = pL[s0 * 64 + row];
    float m1 = pM[s1 * 64 + row], l1 = pL[s1 * 64 + row];
    float m = fmaxf(m0, m1);
    float c0 = __expf(m0 - m), c1 = __expf(m1 - m);
    float inv = 1.f / (l0 * c0 + l1 * c1);
    const float* O0 = pO + ((size_t)s0 * 64 + row) * 64 + cg;
    const float* O1 = pO + ((size_t)s1 * 64 + row) * 64 + cg;
    size_t ob = (size_t)(b * SEQ + q0 + row) * (NH * HD) + h * HD + cg;
#pragma unroll
    for (int j = 0; j < 16; j++) {
        float v = (O0[j] * c0 + O1[j] * c1) * inv;
        u16 hh = f2bf(v);
        outh[ob + j] = hh;
        outl[ob + j] = f2bf(v - bf2f(hh));
    }
}

// ---------------------------------------------------------------- MoE gate/up v3: 64-token tiles, 4 blocks/CU
__global__ __launch_bounds__(256, 4) void moe_gateup3(const u16* __restrict__ xb,
    const u16* __restrict__ wgb, const u16* __restrict__ wub,
    const int* __restrict__ assign_token, const int* __restrict__ offs,
    const int* __restrict__ counts, u16* __restrict__ hbufb)
{
    int e = blockIdx.z;
    int cnt = counts[e];
    int t0 = blockIdx.y * 64;
    if (t0 >= cnt) return;
    int base = offs[e];
    int h0 = blockIdx.x * 64;
    __shared__ __align__(16) u16 As[64 * 64];
    __shared__ __align__(16) u16 Gs[64 * 64];
    __shared__ __align__(16) u16 Us[64 * 64];
    __shared__ int toks[64];
    int tid = threadIdx.x;
    if (tid < 64) {
        int a = t0 + tid;
        toks[tid] = (a < cnt) ? assign_token[base + a] : 0;
    }
    __syncthreads();
    int lane = tid & 63, wv = tid >> 6;
    int wm = wv >> 1, wn = wv & 1;
    int sr = lane >> 3, sc = lane & 7;

    int tokr[2];
#pragma unroll
    for (int i = 0; i < 2; i++) tokr[i] = toks[wv * 16 + i * 8 + sr];

    const u16* wge = wgb + (size_t)e * HID * DIMM;
    const u16* wue = wub + (size_t)e * HID * DIMM;

    f32x4 accg[2][2], accu[2][2];
#pragma unroll
    for (int i = 0; i < 2; i++)
#pragma unroll
        for (int j = 0; j < 2; j++) { accg[i][j] = f32x4{0,0,0,0}; accu[i][j] = f32x4{0,0,0,0}; }

    const int NT = DIMM / 64;   // 16
    int bid = blockIdx.x + gridDim.x * (blockIdx.y + gridDim.y * blockIdx.z);
    int ph = (bid * 5) & (NT - 1);

    for (int tt = 0; tt < NT; ++tt) {
        int k0 = ((tt + ph) & (NT - 1)) << 6;
#pragma unroll
        for (int i = 0; i < 2; i++) {
            int row = wv * 16 + i * 8 + sr;
            int c = sc ^ (row & 7);
            gload16(xb + (size_t)tokr[i] * DIMM + k0 + c * 8, (void*)(As + (wv * 2 + i) * 512));
            gload16(wge + (size_t)(h0 + row) * DIMM + k0 + c * 8, (void*)(Gs + (wv * 2 + i) * 512));
            gload16(wue + (size_t)(h0 + row) * DIMM + k0 + c * 8, (void*)(Us + (wv * 2 + i) * 512));
        }
        __syncthreads();
#pragma unroll
        for (int ks = 0; ks < 2; ++ks) {
            s16x8 af[2], gf[2], uf[2];
#pragma unroll
            for (int mi = 0; mi < 2; mi++)
                af[mi] = ldfrag((const char*)As, wm * 32 + mi * 16 + (lane & 15), ks, lane);
#pragma unroll
            for (int nj = 0; nj < 2; nj++) {
                int row = wn * 32 + nj * 16 + (lane & 15);
                gf[nj] = ldfrag((const char*)Gs, row, ks, lane);
                uf[nj] = ldfrag((const char*)Us, row, ks, lane);
            }
#pragma unroll
            for (int mi = 0; mi < 2; mi++)
#pragma unroll
                for (int nj = 0; nj < 2; nj++) {
                    accg[mi][nj] = mfma16(af[mi], gf[nj], accg[mi][nj]);
                    accu[mi][nj] = mfma16(af[mi], uf[nj], accu[mi][nj]);
                }
        }
        __syncthreads();
    }
#pragma unroll
    for (int mi = 0; mi < 2; mi++)
#pragma unroll
        for (int nj = 0; nj < 2; nj++)
#pragma unroll
            for (int r = 0; r < 4; r++) {
                int row = wm * 32 + mi * 16 + (lane >> 4) * 4 + r;
                if (t0 + row < cnt) {
                    int col = wn * 32 + nj * 16 + (lane & 15);
                    float g = accg[mi][nj][r], u = accu[mi][nj][r];
                    float hh = (g / (1.f + __expf(-g))) * u;
                    hbufb[(size_t)(base + t0 + row) * HID + h0 + col] = f2bf(hh);
                }
            }
}

// ---------------------------------------------------------------- MoE down v7: 128x128, XCD-local remap + K-split x2
// e = bid&7 (expert -> XCD), x = (bid>>3)&7, ks = (bid>>6)&1 (K half), y = bid>>7.
// atomicAdd epilogue makes K-partials exact. Working blocks = bid < 2*256 contiguous -> 2/CU.
// All sharing strides (y:128, x:8, ks:64) are 0 mod 8 -> XCD-local L2 reuse preserved.
__global__ __launch_bounds__(256) void moe_down7(const u16* __restrict__ hbufb,
    const u16* __restrict__ wdb, const int* __restrict__ assign_token,
    const float* __restrict__ assign_w, const int* __restrict__ offs,
    const int* __restrict__ counts, float* __restrict__ out)
{
    int bid = blockIdx.x;
    int e = bid & 7;
    int x = (bid >> 3) & 7;
    int kslice = (bid >> 6) & 1;
    int y = bid >> 7;
    int cnt = counts[e];
    int t0 = y * 128;
    if (t0 >= cnt) return;
    int base = offs[e];
    int d0 = x * 128;
    int kbase = kslice * (HID / 2);      // 0 or 1024
    __shared__ __align__(16) u16 As[128 * 64];
    __shared__ __align__(16) u16 Bs[128 * 64];
    __shared__ int toks[128];
    __shared__ float rw_[128];
    int tid = threadIdx.x;
    if (tid < 128) {
        int a = t0 + tid;
        toks[tid] = (a < cnt) ? assign_token[base + a] : 0;
        rw_[tid] = (a < cnt) ? assign_w[base + a] : 0.f;
    }
    __syncthreads();
    int lane = tid & 63, wv = tid >> 6;
    int wm = wv >> 1, wn = wv & 1;
    int sr = lane >> 3, sc = lane & 7;

    const u16* wde = wdb + (size_t)e * DIMM * HID;

    f32x4 acc[4][4];
#pragma unroll
    for (int i = 0; i < 4; i++)
#pragma unroll
        for (int j = 0; j < 4; j++) acc[i][j] = f32x4{0,0,0,0};

    const int NT = HID / 128;   // 16 per K-half
    int ph = (bid * 5) & (NT - 1);

    for (int tt = 0; tt < NT; ++tt) {
        int k0 = kbase + (((tt + ph) & (NT - 1)) << 6);
#pragma unroll
        for (int i = 0; i < 4; i++) {
            int row = wv * 32 + i * 8 + sr;
            int c = sc ^ (row & 7);
            gload16(hbufb + (size_t)(base + t0 + row) * HID + k0 + c * 8, (void*)(As + (wv * 4 + i) * 512));
            gload16(wde + (size_t)(d0 + row) * HID + k0 + c * 8, (void*)(Bs + (wv * 4 + i) * 512));
        }
        __syncthreads();
#pragma unroll
        for (int ks = 0; ks < 2; ++ks) {
            s16x8 af[4];
#pragma unroll
            for (int mi = 0; mi < 4; mi++)
                af[mi] = ldfrag((const char*)As, wm * 64 + mi * 16 + (lane & 15), ks, lane);
#pragma unroll
            for (int nj = 0; nj < 4; nj++) {
                s16x8 bf = ldfrag((const char*)Bs, wn * 64 + nj * 16 + (lane & 15), ks, lane);
#pragma unroll
                for (int mi = 0; mi < 4; mi++)
                    acc[mi][nj] = mfma16(af[mi], bf, acc[mi][nj]);
            }
        }
        __syncthreads();
    }
#pragma unroll
    for (int mi = 0; mi < 4; mi++)
#pragma unroll
        for (int r = 0; r < 4; r++) {
            int row = wm * 64 + mi * 16 + (lane >> 4) * 4 + r;
            if (t0 + row < cnt) {
                int tok = toks[row];
                float w = rw_[row];
#pragma unroll
                for (int nj = 0; nj < 4; nj++) {
                    int col = d0 + wn * 64 + nj * 16 + (lane & 15);
                    atomicAdd(&out[(size_t)tok * DIMM + col], acc[mi][nj][r] * w);
                }
            }
        }
}

// ---------------------------------------------------------------- launch
extern "C" void kernel_launch(void* const* d_in, const int* in_sizes, int n_in,
                              void* d_out, int out_size, void* d_ws, size_t ws_size,
                              hipStream_t stream)
{
    const float* x      = (const float*)d_in[0];
    const float* cs     = (const float*)d_in[1];
    const float* sn     = (const float*)d_in[2];
    const float* w_na   = (const float*)d_in[3];
    const float* wq     = (const float*)d_in[4];
    const float* wk     = (const float*)d_in[5];
    const float* wv     = (const float*)d_in[6];
    const float* wo     = (const float*)d_in[7];
    const float* w_nf   = (const float*)d_in[8];
    const float* rw     = (const float*)d_in[9];
    const float* rb     = (const float*)d_in[10];
    const float* wg     = (const float*)d_in[11];
    const float* wu     = (const float*)d_in[12];
    const float* wd     = (const float*)d_in[13];
    float* out = (float*)d_out;

    const size_t F = 1024 * 1024;
    float* wsf = (float*)d_ws;

    // layout (float units):
    float* qkvb = wsf;                            // 0..3F     [2048][1536] fp32 (dead after prep2 -> attn partials)
    float* tail = wsf + 3 * F;                    // 3..3.5F   routing scratch
    u16* qsh    = (u16*)(wsf + 3 * F + F / 2);    // 3.5..4.5F [2048][1024]
    u16* qsl    = (u16*)(wsf + 4 * F + F / 2);    // 4.5..5.5F
    u16* ksh    = (u16*)(wsf + 5 * F + F / 2);    // 5.5..5.75F [2048][256]
    u16* ksl    = (u16*)(wsf + 5 * F + 3 * F / 4);// 5.75..6F
    u16* vth    = (u16*)(wsf + 6 * F);            // 6..6.25F  [256][2048]
    u16* vtl    = (u16*)(wsf + 6 * F + F / 4);    // 6.25..6.5F
    u16* xn2b   = (u16*)(wsf + 6 * F + F / 2);    // 6.5..7.5F [2048][1024]
    u16* hbufb  = (u16*)(wsf + 7 * F + F / 2);    // 7.5..11.5F (MoE h, 8M u16)
    u16* xnh    = (u16*)(wsf + 7 * F + F / 2);    //   alias 7.5..8.5F (dead before moe)
    u16* xnl    = (u16*)(wsf + 8 * F + F / 2);    //   alias 8.5..9.5F
    u16* attnh  = (u16*)(wsf + 9 * F + F / 2);    //   alias 9.5..10.5F
    u16* attnl  = (u16*)(wsf + 10 * F + F / 2);   //   alias 10.5..11.5F
    u16* wgb    = (u16*)(wsf + 11 * F + F / 2);   // 11.5..19.5F
    u16* wub    = (u16*)(wsf + 19 * F + F / 2);   // 19.5..27.5F
    u16* wdb    = (u16*)(wsf + 27 * F + F / 2);   // 27.5..35.5F
    u16* wqkvoh = (u16*)(wsf + 35 * F + F / 2);   // 35.5..36.75F
    u16* wqkvol = (u16*)(wsf + 36 * F + 3 * F / 4); // 36.75..38F

    int*   top_idx      = (int*)tail;                     // 4096
    float* top_w        = tail + 4096;                    // 4096
    int*   counts       = (int*)(tail + 8192);            // 8
    int*   offs         = (int*)(tail + 8192) + 8;        // 8
    int*   assign_token = (int*)(tail + 8192) + 32;       // 4096
    float* assign_w     = tail + 8192 + 32 + 4096;        // 4096

    // attn partials aliased over dead qkvb: 512 x (64x64 fp32) + m/l
    float* pO = qkvb;                      // 512*4096 = 2,097,152 floats
    float* pM = qkvb + 2097152;            // 32768
    float* pL = qkvb + 2097152 + 32768;    // 32768  (total 2.16M < 3M)

    const int CV1 = 5242880;   // 5M float4    (qkv window)
    const int CV2 = 8912896;   // 8.5M         (attn window: 3.5M)
    const int CV3 = 12582912;  // 12M          (o window: 3.5M)

    // 1. qkvo weight split-cvt + rmsnorm(attn)  [merged]
    prep1<<<3072, 256, 0, stream>>>(wq, wk, wv, wo, wqkvoh, wqkvol, x, w_na, xnh, xnl);
    // 2. fused qkv projection + MoE cvt chunk 1  [384 gemm + 1280 cvt blocks]
    gemm_cvt<<<384 + 1280, 256, 0, stream>>>(xnh, xnl, wqkvoh, wqkvol,
                                             qkvb, nullptr, N_TOK, QKVW, DIMM, QKVW,
                                             QKVW / 64, 16,
                                             wg, wu, wd, wgb, wub, wdb, 0, CV1, 1280);
    // 3. RoPE (q+k) + V transpose  [merged]
    prep2<<<5248, 256, 0, stream>>>(qkvb, cs, sn, qsh, qsl, ksh, ksl, vth, vtl);
    // 4. attention (kt-split heavy tiles) + MoE cvt chunk 2  [768 attn + 1024 cvt blocks]
    attn_cvt<<<1792, 256, 0, stream>>>(qsh, qsl, ksh, ksl, vth, vtl, attnh, attnl,
                                       pO, pM, pL,
                                       wg, wu, wd, wgb, wub, wdb, CV1, CV2, 1024);
    // 4.5 flash-merge of heavy-tile halves
    attn_combine<<<256, 256, 0, stream>>>(pO, pM, pL, attnh, attnl);
    // 5. output projection + residual + MoE cvt chunk 3  [256 gemm + 768 cvt blocks]
    gemm_cvt<<<256 + 768, 256, 0, stream>>>(attnh, attnl,
                                            wqkvoh + (size_t)1536 * 1024, wqkvol + (size_t)1536 * 1024,
                                            out, x, N_TOK, DIMM, NH * HD, DIMM,
                                            DIMM / 64, 16,
                                            wg, wu, wd, wgb, wub, wdb, CV2, CV3, 768);
    // 6. rmsnorm (ffn) + router logits + top2  [fused]
    rmsnorm_router<<<N_TOK, 256, 0, stream>>>(out, w_nf, rw, rb, xn2b, top_idx, top_w);
    // 7. routing build
    route_build<<<1, 256, 0, stream>>>(top_idx, top_w, counts, offs, assign_token, assign_w);
    // 8-9. MoE (gateup unchanged; down K-split x2 — the measured optimum)
    moe_gateup3<<<dim3(HID / 64, 32, NEXP), 256, 0, stream>>>(xn2b, wgb, wub, assign_token, offs, counts, hbufb);
    moe_down7<<<2048, 256, 0, stream>>>(hbufb, wdb, assign_token, assign_w, offs, counts, out);
}